// Round 5
// baseline (228.149 us; speedup 1.0000x reference)
//
#include <hip/hip_runtime.h>
#include <math.h>

#define N_NODES 20000
#define N_EDGES 320000
#define DIM 64
#define SUB 16
#define NRBF 8
#define NB 5
#define LAYERS 3
#define FCIN (NRBF*SUB*NB + SUB)   // 656
#define KPAD 672                   // 21 * 32
#define NKK 21
#define HD 64
#define CUTOFF 5.0f
#define LOG2F_ 0.69314718055994530942f
#define TSTRIDE 680                // LDS tile row stride (ushorts): 2-way banks only

typedef __attribute__((ext_vector_type(8))) short short8;
typedef __attribute__((ext_vector_type(4))) float float4v;
typedef __attribute__((ext_vector_type(4))) unsigned short ushort4v;
typedef __attribute__((ext_vector_type(2))) unsigned int uint2v;

__device__ __forceinline__ float ssp(float x) {
    float sp = fmaxf(x, 0.0f) + log1pf(expf(-fabsf(x)));
    return sp - LOG2F_;
}

__device__ __forceinline__ unsigned short f2bf(float x) {
    unsigned int u = __float_as_uint(x);
    unsigned int r = (u + 0x7FFFu + ((u >> 16) & 1u)) >> 16;
    return (unsigned short)r;
}
__device__ __forceinline__ float bf2f(unsigned short s) {
    unsigned int u = ((unsigned int)s) << 16;
    return __uint_as_float(u);
}

// --- one-time kernels -------------------------------------------------------

__global__ void k_rowptr(const int* __restrict__ esrc, int* __restrict__ rowptr) {
    int n = blockIdx.x * blockDim.x + threadIdx.x;
    if (n > N_NODES) return;
    int a = 0, b = N_EDGES;
    while (a < b) { int m = (a + b) >> 1; if (esrc[m] < n) a = m + 1; else b = m; }
    rowptr[n] = a;
}

// u16[e][g*12+j] = bf16( sw[e] * rb[r] * bo[b] ), p=g+4j, r=p/5, b=p%5; j=10,11 pad=0
__global__ void k_u(const float* __restrict__ dist, const float* __restrict__ sw,
                    const float* __restrict__ bo, unsigned short* __restrict__ u16) {
    int i = blockIdx.x * blockDim.x + threadIdx.x;
    if (i >= N_EDGES * 48) return;
    int e = i / 48, t = i - e * 48;
    int g = t / 12, j = t - g * 12;
    float v = 0.0f;
    if (j < 10) {
        int p = g + 4 * j;
        int r = p / 5, b = p - r * 5;
        float mu = (CUTOFF / (NRBF - 1)) * (float)r;
        float inv_sigma = (float)NRBF / CUTOFF;
        float z = (dist[e] - mu) * inv_sigma;
        v = sw[e] * expf(-0.5f * z * z) * bo[e * NB + b];
    }
    u16[i] = f2bf(v);
}

// Pack weights into MFMA B-fragment order (bf16). Same layout as round 3.
__global__ void k_packw(const float* __restrict__ w0, const float* __restrict__ w1,
                        const float* __restrict__ w2,
                        short* __restrict__ w0f, short* __restrict__ w1f,
                        short* __restrict__ w2f) {
    int i = blockIdx.x * blockDim.x + threadIdx.x;
    const int SZ0 = LAYERS * NKK * 4 * 64 * 8;       // 129024
    const int SZ12 = LAYERS * 2 * 4 * 64 * 8;        // 12288
    if (i < SZ0) {
        int j = i & 7, t = i >> 3;
        int lane = t & 63; t >>= 6;
        int nf = t & 3; t >>= 2;
        int kk = t % NKK, l = t / NKK;
        int kp = kk * 32 + (lane >> 4) * 8 + j;
        int col = nf * 16 + (lane & 15);
        float v = 0.0f;
        if (kp < FCIN) {
            int orig;
            if (kp < 640) {
                int j10 = kp >> 6, rem = kp & 63, g = rem >> 4, s = rem & 15;
                int p = g + 4 * j10;
                orig = (p / 5) * 80 + s * 5 + (p - 5 * (p / 5));
            } else orig = kp;
            v = w0[((size_t)l * FCIN + orig) * HD + col];
        }
        w0f[i] = (short)f2bf(v);
        return;
    }
    i -= SZ0;
    if (i < 2 * SZ12) {
        const float* W = (i < SZ12) ? w1 : w2;
        short* Wf = (i < SZ12) ? w1f : w2f;
        int ii = (i < SZ12) ? i : i - SZ12;
        int j = ii & 7, t = ii >> 3;
        int lane = t & 63; t >>= 6;
        int nf = t & 3; t >>= 2;
        int kk = t & 1, l = t >> 1;
        int kp = kk * 32 + (lane >> 4) * 8 + j;
        int col = nf * 16 + (lane & 15);
        Wf[ii] = (short)f2bf(W[((size_t)l * HD + kp) * HD + col]);
    }
}

__global__ void k_init_xi(const int* __restrict__ species,
                          const float* __restrict__ Wsp,
                          float* __restrict__ xi) {
    int i = blockIdx.x * blockDim.x + threadIdx.x;
    if (i >= N_NODES * DIM) return;
    int n = i >> 6, d = i & 63;
    xi[i] = Wsp[species[n] * DIM + d];
}

// --- per-layer kernels ------------------------------------------------------

// h = xi @ W_sm[l] + b_sm[l]; si fp32, mi bf16 (feeds the edge gather)
__global__ void k_h(const float* __restrict__ xi,
                    const float* __restrict__ Wsm, const float* __restrict__ bsm,
                    float* __restrict__ si, unsigned short* __restrict__ mi16, int l) {
    int i = blockIdx.x * blockDim.x + threadIdx.x;
    if (i >= N_NODES * 2 * SUB) return;
    int n = i >> 5, j = i & 31;
    const float* W = Wsm + l * DIM * 2 * SUB;
    const float* xr = xi + n * DIM;
    float v = bsm[l * 2 * SUB + j];
    #pragma unroll
    for (int d = 0; d < DIM; ++d) v = fmaf(xr[d], W[d * 2 * SUB + j], v);
    if (j < SUB) si[n * SUB + j] = v;
    else         mi16[n * SUB + (j - SUB)] = f2bf(v);
}

// Edge-parallel gather: medge[e][0:16] = mi16[edst[e]][0:16]. uint2 = 4 bf16/lane.
__global__ void k_gather(const int* __restrict__ edst,
                         const unsigned short* __restrict__ mi16,
                         unsigned short* __restrict__ medge) {
    int i = blockIdx.x * blockDim.x + threadIdx.x;   // i < E*4
    if (i >= N_EDGES * 4) return;
    int e = i >> 2, q = i & 3;
    int dst = edst[e];
    ((uint2v*)medge)[i] = ((const uint2v*)mi16)[dst * 4 + q];
}

// Fused aggregation + MLP. 16 nodes/block, 4 waves.
// Phase 1: wave w aggregates nodes n0+4w..n0+4w+3 into LDS tile (cat' layout).
// Phase 2: MFMA fc0 (A from LDS tile) -> fc1 -> fc2 + residual.
__global__ __launch_bounds__(256) void k_fused(
    const int* __restrict__ rowptr,
    const unsigned short* __restrict__ u16,
    const unsigned short* __restrict__ medge,
    const float* __restrict__ si,
    const short* __restrict__ w0f, const float* __restrict__ b0,
    const short* __restrict__ w1f, const float* __restrict__ b1,
    const short* __restrict__ w2f, const float* __restrict__ b2,
    float* __restrict__ xi, int l)
{
    __shared__ __align__(16) unsigned short tile[16][TSTRIDE];
    __shared__ __align__(16) unsigned short h1[16][72];
    __shared__ __align__(16) unsigned short h2[16][72];
    const int lane = threadIdx.x & 63;
    const int w = threadIdx.x >> 6;
    const int n0 = blockIdx.x * 16;
    const int r = lane & 15, g = lane >> 4;
    const int s = r;   // aggregation: s = lane&15

    // ---- phase 1: aggregation into LDS tile ----
    int bounds[5];
    #pragma unroll
    for (int i = 0; i < 5; ++i) bounds[i] = rowptr[n0 + 4 * w + i];

    for (int nn = 0; nn < 4; ++nn) {
        const int lo = bounds[nn], hi = bounds[nn + 1];
        float a0=0,a1=0,a2=0,a3=0,a4=0,a5=0,a6=0,a7=0,a8=0,a9=0;
        if (lo < hi) {
            ushort4v ua, ub; unsigned int uc; float m;
            {
                const unsigned short* up = u16 + (size_t)lo * 48 + g * 12;
                ua = *(const ushort4v*)(up);
                ub = *(const ushort4v*)(up + 4);
                uc = *(const unsigned int*)(up + 8);
                m = bf2f(medge[(size_t)lo * 16 + s]);
            }
            for (int e = lo; ; ) {
                ushort4v cua = ua, cub = ub; unsigned int cuc = uc; float cm = m;
                ++e;
                if (e < hi) {
                    const unsigned short* up = u16 + (size_t)e * 48 + g * 12;
                    ua = *(const ushort4v*)(up);
                    ub = *(const ushort4v*)(up + 4);
                    uc = *(const unsigned int*)(up + 8);
                    m = bf2f(medge[(size_t)e * 16 + s]);
                }
                a0 = fmaf(bf2f(cua.x), cm, a0); a1 = fmaf(bf2f(cua.y), cm, a1);
                a2 = fmaf(bf2f(cua.z), cm, a2); a3 = fmaf(bf2f(cua.w), cm, a3);
                a4 = fmaf(bf2f(cub.x), cm, a4); a5 = fmaf(bf2f(cub.y), cm, a5);
                a6 = fmaf(bf2f(cub.z), cm, a6); a7 = fmaf(bf2f(cub.w), cm, a7);
                a8 = fmaf(bf2f((unsigned short)(cuc & 0xFFFFu)), cm, a8);
                a9 = fmaf(bf2f((unsigned short)(cuc >> 16)), cm, a9);
                if (e >= hi) break;
            }
        }
        const int row = 4 * w + nn;
        unsigned short* tp = &tile[row][0];
        tp[0*64+lane]=f2bf(a0); tp[1*64+lane]=f2bf(a1); tp[2*64+lane]=f2bf(a2);
        tp[3*64+lane]=f2bf(a3); tp[4*64+lane]=f2bf(a4); tp[5*64+lane]=f2bf(a5);
        tp[6*64+lane]=f2bf(a6); tp[7*64+lane]=f2bf(a7); tp[8*64+lane]=f2bf(a8);
        tp[9*64+lane]=f2bf(a9);
        if (lane < SUB)      tp[640 + lane] = f2bf(si[(size_t)(n0 + row) * SUB + lane]);
        else if (lane < 32)  tp[640 + lane] = 0;   // pad cols 656..671
    }
    __syncthreads();

    // ---- phase 2: MFMA MLP ----
    // fc0: K=672, 21 MFMA steps, 2 independent chains; A from LDS tile row r
    const short* Bp = w0f + ((size_t)l * NKK * 256 + w * 64 + lane) * 8;
    float bv = b0[l * HD + w * 16 + r];
    float4v accA = {bv, bv, bv, bv};
    float4v accB = {0.f, 0.f, 0.f, 0.f};
    #pragma unroll 5
    for (int kk = 0; kk < 20; kk += 2) {
        short8 aA = *(const short8*)((const short*)&tile[r][kk * 32 + g * 8]);
        short8 bA = *(const short8*)(Bp + (size_t)kk * 2048);
        accA = __builtin_amdgcn_mfma_f32_16x16x32_bf16(aA, bA, accA, 0, 0, 0);
        short8 aB = *(const short8*)((const short*)&tile[r][(kk + 1) * 32 + g * 8]);
        short8 bB = *(const short8*)(Bp + (size_t)(kk + 1) * 2048);
        accB = __builtin_amdgcn_mfma_f32_16x16x32_bf16(aB, bB, accB, 0, 0, 0);
    }
    {
        short8 a = *(const short8*)((const short*)&tile[r][20 * 32 + g * 8]);
        short8 b = *(const short8*)(Bp + (size_t)20 * 2048);
        accA = __builtin_amdgcn_mfma_f32_16x16x32_bf16(a, b, accA, 0, 0, 0);
    }
    #pragma unroll
    for (int i = 0; i < 4; ++i)
        h1[g * 4 + i][w * 16 + r] = f2bf(ssp(accA[i] + accB[i]));
    __syncthreads();

    // fc1
    bv = b1[l * HD + w * 16 + r];
    float4v acc1 = {bv, bv, bv, bv};
    #pragma unroll
    for (int kk = 0; kk < 2; ++kk) {
        short8 a = *(const short8*)((const short*)&h1[r][kk * 32 + g * 8]);
        short8 b = *(const short8*)(w1f + ((size_t)(l * 2 + kk) * 256 + w * 64 + lane) * 8);
        acc1 = __builtin_amdgcn_mfma_f32_16x16x32_bf16(a, b, acc1, 0, 0, 0);
    }
    #pragma unroll
    for (int i = 0; i < 4; ++i)
        h2[g * 4 + i][w * 16 + r] = f2bf(ssp(acc1[i]));
    __syncthreads();

    // fc2 + residual
    bv = b2[l * DIM + w * 16 + r];
    float4v acc2 = {bv, bv, bv, bv};
    #pragma unroll
    for (int kk = 0; kk < 2; ++kk) {
        short8 a = *(const short8*)((const short*)&h2[r][kk * 32 + g * 8]);
        short8 b = *(const short8*)(w2f + ((size_t)(l * 2 + kk) * 256 + w * 64 + lane) * 8);
        acc2 = __builtin_amdgcn_mfma_f32_16x16x32_bf16(a, b, acc2, 0, 0, 0);
    }
    #pragma unroll
    for (int i = 0; i < 4; ++i)
        xi[(size_t)(n0 + g * 4 + i) * DIM + w * 16 + r] += acc2[i];
}

extern "C" void kernel_launch(void* const* d_in, const int* in_sizes, int n_in,
                              void* d_out, int out_size, void* d_ws, size_t ws_size,
                              hipStream_t stream) {
    const int*   species = (const int*)  d_in[0];
    const int*   esrc    = (const int*)  d_in[1];
    const int*   edst    = (const int*)  d_in[2];
    const float* dist    = (const float*)d_in[3];
    const float* sw      = (const float*)d_in[4];
    const float* bo      = (const float*)d_in[5];
    const float* Wsp     = (const float*)d_in[6];
    const float* Wsm     = (const float*)d_in[7];
    const float* bsm     = (const float*)d_in[8];
    const float* w0      = (const float*)d_in[9];
    const float* b0      = (const float*)d_in[10];
    const float* w1      = (const float*)d_in[11];
    const float* b1      = (const float*)d_in[12];
    const float* w2      = (const float*)d_in[13];
    const float* b2      = (const float*)d_in[14];

    float* xi = (float*)d_out;   // N x 64 fp32, updated in place

    // ws layout: u16 E*48 ush | si N*16 f | mi16 N*16 ush | medge E*16 ush |
    //            w0f | w1f | w2f | rowptr
    unsigned short* u16   = (unsigned short*)d_ws;
    float*          si    = (float*)(u16 + (size_t)N_EDGES * 48);
    unsigned short* mi16  = (unsigned short*)(si + (size_t)N_NODES * SUB);
    unsigned short* medge = mi16 + (size_t)N_NODES * SUB;
    short* w0f = (short*)(medge + (size_t)N_EDGES * 16);
    short* w1f = w0f + (size_t)LAYERS * NKK * 2048;
    short* w2f = w1f + (size_t)LAYERS * 2 * 2048;
    int* rowptr = (int*)(w2f + (size_t)LAYERS * 2 * 2048);

    k_rowptr<<<(N_NODES + 1 + 255) / 256, 256, 0, stream>>>(esrc, rowptr);
    k_u<<<(N_EDGES * 48 + 255) / 256, 256, 0, stream>>>(dist, sw, bo, u16);
    {
        int total = LAYERS * NKK * 2048 + 2 * LAYERS * 2 * 2048;
        k_packw<<<(total + 255) / 256, 256, 0, stream>>>(w0, w1, w2, w0f, w1f, w2f);
    }
    k_init_xi<<<(N_NODES * DIM + 255) / 256, 256, 0, stream>>>(species, Wsp, xi);

    for (int l = 0; l < LAYERS; ++l) {
        k_h<<<(N_NODES * 2 * SUB + 255) / 256, 256, 0, stream>>>(xi, Wsm, bsm, si, mi16, l);
        k_gather<<<(N_EDGES * 4 + 255) / 256, 256, 0, stream>>>(edst, mi16, medge);
        k_fused<<<N_NODES / 16, 256, 0, stream>>>(rowptr, u16, medge, si,
                                                  w0f, b0, w1f, b1, w2f, b2, xi, l);
    }
}